// Round 10
// baseline (209.638 us; speedup 1.0000x reference)
//
#include <hip/hip_runtime.h>
#include <cstdint>
#include <cstddef>

// Problem constants (reference: B=4, N=2048, DIM=256, heads=8, groups=2)
#define B_    4
#define NPT   2048
#define DIM_  256
#define QKVW  768   // 3*DIM
#define XLEN  2097152   // 8192*256
#define QLEN  196608    // 768*256
#define PLEN  65536     // 256*256
#define TOTC  (XLEN + QLEN + 2 * PLEN)  // 2424832

typedef unsigned short ushort_t;
typedef unsigned long long u64;
typedef short bf16x8 __attribute__((ext_vector_type(8)));
typedef float f32x4 __attribute__((ext_vector_type(4)));

__device__ __forceinline__ float gelu_f(float x) {
  return 0.5f * x * (1.0f + erff(x * 0.70710678118654752440f));
}

// Fast gelu: A&S 7.1.26 erf (max abs err 1.5e-7).
__device__ __forceinline__ float gelu_fast(float x) {
  const float is2 = 0.70710678118654752440f;
  float z = x * is2;
  float az = __builtin_fabsf(z);
  float t = __builtin_amdgcn_rcpf(fmaf(0.3275911f, az, 1.0f));
  float p = fmaf(1.061405429f, t, -1.453152027f);
  p = fmaf(p, t, 1.421413741f);
  p = fmaf(p, t, -0.284496736f);
  p = fmaf(p, t, 0.254829592f);
  p = p * t;
  float e = __expf(-az * az);
  float er = fmaf(-p, e, 1.0f);
  er = __builtin_copysignf(er, x);
  return 0.5f * x * (1.0f + er);
}

__device__ __forceinline__ ushort_t f2bf(float f) {
  unsigned u = __float_as_uint(f);
  unsigned r = (u + 0x7fffu + ((u >> 16) & 1u)) >> 16;
  return (ushort_t)r;
}
__device__ __forceinline__ float bf2f(ushort_t h) {
  return __uint_as_float(((unsigned)h) << 16);
}
// unpack a packed pair of bf16 (little-endian: low half = even channel)
__device__ __forceinline__ float bflo(unsigned p) {
  return __uint_as_float(p << 16);
}
__device__ __forceinline__ float bfhi(unsigned p) {
  return __uint_as_float(p & 0xffff0000u);
}

// butterfly sum over 16-lane rows via ds_swizzle (xor 1,2,4,8; and=0x1F).
// All 16 lanes of each row end with the row sum. LDS-pipe, no DPP hazards.
__device__ __forceinline__ float bfly16_sum(float x) {
  x += __int_as_float(__builtin_amdgcn_ds_swizzle(__float_as_int(x), 0x041F));
  x += __int_as_float(__builtin_amdgcn_ds_swizzle(__float_as_int(x), 0x081F));
  x += __int_as_float(__builtin_amdgcn_ds_swizzle(__float_as_int(x), 0x101F));
  x += __int_as_float(__builtin_amdgcn_ds_swizzle(__float_as_int(x), 0x201F));
  return x;
}

__device__ __forceinline__ unsigned mbcnt64(u64 bal) {
  return __builtin_amdgcn_mbcnt_hi(
      (unsigned)(bal >> 32), __builtin_amdgcn_mbcnt_lo((unsigned)bal, 0u));
}

// scale a bf16x8 B-fragment by av[k] (8 consecutive k's from global, L1-hot)
__device__ __forceinline__ bf16x8 scale_bf(bf16x8 v, const float* avk) {
  bf16x8 r;
#pragma unroll
  for (int e = 0; e < 8; e++) {
    float f = bf2f((ushort_t)v[e]) * avk[e];
    r[e] = (short)f2bf(f);
  }
  return r;
}

// ---------------------------------------------------------------------------
// CONVERT: bf16 conversion of x and transposed weights; zeroes `part`.
// ---------------------------------------------------------------------------
__global__ __launch_bounds__(256) void convert_kernel(
    const float* __restrict__ x, const float* __restrict__ Wqkv,
    const float* __restrict__ Wproj, const float* __restrict__ Whead,
    ushort_t* __restrict__ xbf, ushort_t* __restrict__ WqkvT,
    ushort_t* __restrict__ WprojT, ushort_t* __restrict__ WheadT,
    float* __restrict__ part) {
  int base = blockIdx.x * 256 + threadIdx.x;
  if (base < 1024) part[base] = 0.f;
  for (int i = base; i < TOTC; i += 2048 * 256) {
    if (i < XLEN) {
      xbf[i] = f2bf(x[i]);
    } else if (i < XLEN + QLEN) {
      int e = i - XLEN;                  // input-major: coalesced read
      int k = e / 768, n = e - k * 768;
      WqkvT[n * 256 + k] = f2bf(Wqkv[e]);
    } else if (i < XLEN + QLEN + PLEN) {
      int e = i - XLEN - QLEN;
      int k = e >> 8, n = e & 255;
      WprojT[n * 256 + k] = f2bf(Wproj[e]);
    } else {
      int e = i - XLEN - QLEN - PLEN;
      int k = e >> 8, n = e & 255;
      WheadT[n * 256 + k] = f2bf(Whead[e]);
    }
  }
}

// ---------------------------------------------------------------------------
// FUSED KNN + GEMM0 v5 (R9): grid 2048 x 256 thr.
//   Waves 0-1: TWO KNN queries each (wqA = bid*4 + w*2, wqB = wqA+1 --
//     A even => A,B always same batch; pos loads SHARED between the pair).
//     2-query interleave doubles per-wave ILP in the latency-bound dist/
//     compact/rank phases (model: ~8 us issue vs ~30 us measured at ~5
//     resident waves/SIMD => latency-bound; more ILP ~= more waves).
//   Waves 2-3: gemm0 tiles t = bid*2 + (w-2), guard t<3072 (adjacent tiles
//     share A-rows -> L1 reuse). Wave-level mix keeps MFMA+VALU co-resident.
// KNN per query unchanged (bit-identical): ballot bisect seeded
// [0.0078, 0.25]; ballot+mbcnt compact; rank-select => exact argsort order.
// Rank loop runs to max(mtA,mtB); reads past a query's own total hit ~0ULL
// fillers (compare false) -- harmless, no guards needed.
// ---------------------------------------------------------------------------
__global__ __launch_bounds__(256) void knn_gemm0_kernel(
    const float* __restrict__ pos, int* __restrict__ idx_out,
    const ushort_t* __restrict__ A, const ushort_t* __restrict__ BT,
    ushort_t* __restrict__ C) {
  __shared__ u64 buf[4][128];
  int tid = threadIdx.x;
  int w = tid >> 6, lane = tid & 63;
  if (w >= 2) {
    // ---- gemm0: C[64x32] = A @ BT^T (bf16 out), K=256, N=768 ----
    int t0 = blockIdx.x * 2 + (w - 2);             // 0..4095
    if (t0 >= 3072) return;
    constexpr int K = 256;
    constexpr int N = 768;
    int quad = lane >> 4, r16 = lane & 15;
    int m0 = (t0 / 24) * 64, n0 = (t0 % 24) * 32;
    const ushort_t* Ap = A + (size_t)(m0 + r16) * K + quad * 8;
    const ushort_t* Bp = BT + (size_t)(n0 + r16) * K + quad * 8;
    f32x4 acc[4][2] = {};
    bf16x8 af[4], bfv[2], af2[4], bf2[2];
#pragma unroll
    for (int i = 0; i < 4; i++) af[i] = *(const bf16x8*)(Ap + (size_t)i * 16 * K);
#pragma unroll
    for (int j = 0; j < 2; j++) bfv[j] = *(const bf16x8*)(Bp + (size_t)j * 16 * K);
#pragma unroll
    for (int kc = 0; kc < 8; kc++) {
      if (kc < 7) {
        int ko = (kc + 1) * 32;
#pragma unroll
        for (int i = 0; i < 4; i++)
          af2[i] = *(const bf16x8*)(Ap + (size_t)i * 16 * K + ko);
#pragma unroll
        for (int j = 0; j < 2; j++)
          bf2[j] = *(const bf16x8*)(Bp + (size_t)j * 16 * K + ko);
      }
#pragma unroll
      for (int i = 0; i < 4; i++) {
        acc[i][0] = __builtin_amdgcn_mfma_f32_16x16x32_bf16(af[i], bfv[0], acc[i][0], 0, 0, 0);
        acc[i][1] = __builtin_amdgcn_mfma_f32_16x16x32_bf16(af[i], bfv[1], acc[i][1], 0, 0, 0);
      }
#pragma unroll
      for (int i = 0; i < 4; i++) af[i] = af2[i];
      bfv[0] = bf2[0]; bfv[1] = bf2[1];
    }
#pragma unroll
    for (int i = 0; i < 4; i++) {
#pragma unroll
      for (int j = 0; j < 2; j++) {
        int col = n0 + j * 16 + r16;
#pragma unroll
        for (int r = 0; r < 4; r++) {
          int row = m0 + i * 16 + quad * 4 + r;
          C[(size_t)row * N + col] = f2bf(acc[i][j][r]);
        }
      }
    }
    return;
  }
  // ---- KNN: wave w (0..1) handles queries wqA = bid*4+w*2 and wqA+1 ----
  int wqA = blockIdx.x * 4 + w * 2;
  int wqB = wqA + 1;
  int b = wqA >> 11;                    // A even => same batch for A,B
  int nA = wqA & (NPT - 1), nB = wqB & (NPT - 1);
  const float* pb = pos + (size_t)b * NPT * 3;
  float qx0 = pb[nA * 3 + 0], qy0 = pb[nA * 3 + 1], qz0 = pb[nA * 3 + 2];
  float qx1 = pb[nB * 3 + 0], qy1 = pb[nB * 3 + 1], qz1 = pb[nB * 3 + 2];
  float d0[32], d1[32];
  {
#pragma clang fp contract(off)
#pragma unroll
    for (int s = 0; s < 32; s++) {
      int j = lane + (s << 6);
      float px = pb[j * 3 + 0], py = pb[j * 3 + 1], pz = pb[j * 3 + 2];
      float ax = qx0 - px, ay = qy0 - py, az = qz0 - pz;
      float bx = qx1 - px, by = qy1 - py, bz = qz1 - pz;
      float da = ax * ax;
      da = da + ay * ay;
      da = da + az * az;
      float db = bx * bx;
      db = db + by * by;
      db = db + bz * bz;
      d0[s] = da;
      d1[s] = db;
    }
  }
  // --- bisect threshold per query (seeded window; [32,64] break) ---
  auto bisect = [&](const float (&dd)[32]) -> float {
    unsigned lo = 0x3C000000u;  // dist^2 = 0.0078 (r=0.088): count<32 typ.
    unsigned hi = 0x3E800001u;  // dist^2 = 0.25+  (r=0.5):   count>=32 certain
    for (int it = 0; it < 31 && hi - lo > 1; ++it) {
      unsigned mid = (lo + hi) >> 1;
      float fm = __uint_as_float(mid);  // positive: bit order == value order
      int c = 0;
#pragma unroll
      for (int s = 0; s < 32; s++)
        c += (int)__popcll(__ballot(dd[s] < fm));
      if (c >= 32) { hi = mid; if (c <= 64) break; }
      else lo = mid;
    }
    return __uint_as_float(hi);         // invariant: count(T) >= 32
  };
  float fT0 = bisect(d0);
  float fT1 = bisect(d1);
  // --- dual compact into wave-private LDS slots (ballot+mbcnt prefix) ---
  int s0 = w * 2, s1 = w * 2 + 1;
  buf[s0][lane] = ~0ULL; buf[s0][lane + 64] = ~0ULL;
  buf[s1][lane] = ~0ULL; buf[s1][lane + 64] = ~0ULL;
  __builtin_amdgcn_wave_barrier();
  asm volatile("s_waitcnt lgkmcnt(0)" ::: "memory");
  unsigned c0 = 0, c1 = 0;
#pragma unroll
  for (int s = 0; s < 32; s++) {
    int j = lane + (s << 6);
    bool m0 = d0[s] < fT0, m1 = d1[s] < fT1;
    u64 bal0 = __ballot(m0), bal1 = __ballot(m1);
    unsigned p0 = c0 + mbcnt64(bal0), p1 = c1 + mbcnt64(bal1);
    if (m0 && p0 < 128u)
      buf[s0][p0] = ((u64)__float_as_uint(d0[s]) << 32) | (unsigned)j;
    if (m1 && p1 < 128u)
      buf[s1][p1] = ((u64)__float_as_uint(d1[s]) << 32) | (unsigned)j;
    c0 += (unsigned)__popcll(bal0);
    c1 += (unsigned)__popcll(bal1);
  }
  __builtin_amdgcn_wave_barrier();
  asm volatile("s_waitcnt lgkmcnt(0)" ::: "memory");
  if (c0 > 128u) c0 = 128u;
  if (c1 > 128u) c1 = 128u;
  unsigned mt0 = (c0 + 7u) & ~7u, mt1 = (c1 + 7u) & ~7u;
  unsigned mt = mt0 > mt1 ? mt0 : mt1;
  // --- dual rank-select: rank = #keys smaller; rank<32 -> idx_out[rank] ---
  u64 k0A = buf[s0][lane], k1A = buf[s0][lane + 64];
  u64 k0B = buf[s1][lane], k1B = buf[s1][lane + 64];
  int r0A = 0, r1A = 0, r0B = 0, r1B = 0;
  for (unsigned i = 0; i < mt; i += 8) {
#pragma unroll
    for (int t = 0; t < 8; t++) {
      u64 kiA = buf[s0][i + t];        // wave-uniform addr: LDS broadcast
      u64 kiB = buf[s1][i + t];
      r0A += (kiA < k0A) ? 1 : 0;
      r1A += (kiA < k1A) ? 1 : 0;
      r0B += (kiB < k0B) ? 1 : 0;
      r1B += (kiB < k1B) ? 1 : 0;
    }
  }
  if (r0A < 32) idx_out[(size_t)wqA * 32 + r0A] = (int)(unsigned)(k0A & 0xffffffffULL);
  if (r1A < 32) idx_out[(size_t)wqA * 32 + r1A] = (int)(unsigned)(k1A & 0xffffffffULL);
  if (r0B < 32) idx_out[(size_t)wqB * 32 + r0B] = (int)(unsigned)(k0B & 0xffffffffULL);
  if (r1B < 32) idx_out[(size_t)wqB * 32 + r1B] = (int)(unsigned)(k1B & 0xffffffffULL);
}

// ---------------------------------------------------------------------------
// Register-file MFMA GEMM: ONE wave per 64x32 tile, K=256. No LDS/barriers.
// MODE 1: C = gelu(acc+bias) + colsum atomics (feats_proj)
// MODE 2: C = extra + (A@(B*av)) + bias (av from global, L1-hot)
// ---------------------------------------------------------------------------
template <int MODE>
__global__ __launch_bounds__(64, 4) void gemm_rf(
    const ushort_t* __restrict__ A, const ushort_t* __restrict__ BT,
    const float* __restrict__ bias, const float* __restrict__ extra,
    float* __restrict__ C, float* __restrict__ part,
    const float* __restrict__ av, int N) {
  constexpr int K = 256;
  int lane = threadIdx.x;
  int quad = lane >> 4, r16 = lane & 15;
  int t0 = blockIdx.x;
  int m0 = (t0 >> 3) * 64, n0 = (t0 & 7) * 32;
  int batch = m0 >> 11;
  const ushort_t* Ap = A + (size_t)(m0 + r16) * K + quad * 8;
  const ushort_t* Bp = BT + (size_t)(n0 + r16) * K + quad * 8;
  f32x4 acc[4][2] = {};
  bf16x8 af[4], bf[2], af2[4], bf2[2];
#pragma unroll
  for (int i = 0; i < 4; i++) af[i] = *(const bf16x8*)(Ap + (size_t)i * 16 * K);
#pragma unroll
  for (int j = 0; j < 2; j++) bf[j] = *(const bf16x8*)(Bp + (size_t)j * 16 * K);
#pragma unroll
  for (int kc = 0; kc < 8; kc++) {
    if (kc < 7) {
      int ko = (kc + 1) * 32;
#pragma unroll
      for (int i = 0; i < 4; i++)
        af2[i] = *(const bf16x8*)(Ap + (size_t)i * 16 * K + ko);
#pragma unroll
      for (int j = 0; j < 2; j++)
        bf2[j] = *(const bf16x8*)(Bp + (size_t)j * 16 * K + ko);
    }
    bf16x8 b0 = bf[0], b1 = bf[1];
    if (MODE == 2) {
      const float* avk = av + batch * 256 + kc * 32 + quad * 8;
      b0 = scale_bf(b0, avk);
      b1 = scale_bf(b1, avk);
    }
#pragma unroll
    for (int i = 0; i < 4; i++) {
      acc[i][0] = __builtin_amdgcn_mfma_f32_16x16x32_bf16(af[i], b0, acc[i][0], 0, 0, 0);
      acc[i][1] = __builtin_amdgcn_mfma_f32_16x16x32_bf16(af[i], b1, acc[i][1], 0, 0, 0);
    }
#pragma unroll
    for (int i = 0; i < 4; i++) af[i] = af2[i];
    bf[0] = bf2[0]; bf[1] = bf2[1];
  }
  float cs[2] = {};
#pragma unroll
  for (int i = 0; i < 4; i++) {
#pragma unroll
    for (int j = 0; j < 2; j++) {
      int col = n0 + j * 16 + r16;
#pragma unroll
      for (int r = 0; r < 4; r++) {
        int row = m0 + i * 16 + quad * 4 + r;
        float v = acc[i][j][r];
        if (MODE == 1) { v = gelu_fast(v + bias[col]); cs[j] += v; }
        else if (MODE == 2) v = extra[(size_t)row * 256 + col] + v + bias[col];
        C[(size_t)row * N + col] = v;
      }
    }
  }
  if (MODE == 1) {
#pragma unroll
    for (int j = 0; j < 2; j++) {
      cs[j] += __shfl_xor(cs[j], 16, 64);
      cs[j] += __shfl_xor(cs[j], 32, 64);
    }
    if (quad == 0) {
#pragma unroll
      for (int j = 0; j < 2; j++)
        atomicAdd(&part[batch * 256 + n0 + j * 16 + r16], cs[j]);
    }
  }
}

// ---------------------------------------------------------------------------
// Attention v9 (R9): + XCD-batch-locality swizzle. Default round-robin
// (XCD = linear bid % 8) makes all 8 XCDs gather from all 4 batches (8 MB+
// working set vs 4 MB L2/XCD). Remap so XCD x serves only batch x>>1:
// gather set = k+v = 2 MB bf16 < 4 MB L2. grid.y offset 8192 % 8 == 0 =>
// both groups of a u land on the SAME XCD (shared k/v rows). Pure index
// permutation -- bit-identical output. Core unchanged from v8: bf16 qkv,
// 2 ch/lane, 1-dword k/v pair loads, ds_swizzle butterfly, fixed-max SM.
// ---------------------------------------------------------------------------
template <int NK>
__device__ __forceinline__ void attn_core(
    const ushort_t* __restrict__ kvbase, int lane, const int* sidx,
    const float4* srel, float qSx, float qSy,
    float2 w0, float2 w1, float2 w2, float2 bb,
    float& num0, float& num1, float& den) {
#pragma unroll
  for (int j = 0; j < NK; j++) {
    int jj = __builtin_amdgcn_readfirstlane(sidx[j]);   // wave-uniform -> SGPR
    float4 rr = srel[j];                                // LDS broadcast
    const ushort_t* kb = kvbase + (size_t)jj * QKVW;
    unsigned pk = ((const unsigned*)kb)[lane];          // k pair (1 dword)
    unsigned pv = ((const unsigned*)(kb + 256))[lane];  // v pair (1 dword)
    float kvx = bflo(pk), kvy = bfhi(pk);
    float vvx = bflo(pv), vvy = bfhi(pv);
    float x0 = fmaf(rr.x, w0.x, fmaf(rr.y, w1.x, fmaf(rr.z, w2.x, bb.x)));
    float x1 = fmaf(rr.x, w0.y, fmaf(rr.y, w1.y, fmaf(rr.z, w2.y, bb.y)));
    // gelu_tanh(x) == x * sigmoid(x*(0.0713548163*x^2 + 1.5957691216))
    float z0 = x0 * fmaf(0.0713548163f, x0 * x0, 1.5957691216f);
    float z1 = x1 * fmaf(0.0713548163f, x1 * x1, 1.5957691216f);
    float r0 = x0 * __builtin_amdgcn_rcpf(1.0f + __expf(-z0));
    float r1 = x1 * __builtin_amdgcn_rcpf(1.0f + __expf(-z1));
    float p = fmaf(qSx, kvx, r0) + fmaf(qSy, kvy, r1);
    float logit = bfly16_sum(p);     // head sum over 32 ch, in all 16 lanes
    float e = __expf(logit);
    den += e;
    num0 = fmaf(e, vvx + r0, num0);
    num1 = fmaf(e, vvy + r1, num1);
  }
}

__global__ __launch_bounds__(64) void attn_kernel(
    const ushort_t* __restrict__ qkv, const float* __restrict__ pos,
    const int* __restrict__ knn,
    const float* __restrict__ Wp0, const float* __restrict__ bp0,
    const float* __restrict__ Wp1, const float* __restrict__ bp1,
    ushort_t* __restrict__ xcat) {
  const float SCALE = 0.17677669529663687f;  // 32^-0.5
  int bid = blockIdx.x;
  int xcd = bid & 7;            // XCD-batch-locality swizzle
  int b = xcd >> 1;             // XCD pair {2b,2b+1} serves batch b
  int n = ((bid >> 3) << 1) | (xcd & 1);
  int u = (b << 11) | n;        // original (b,n) index for knn/xcat
  int g = blockIdx.y;           // group
  int lane = threadIdx.x;       // 0..63, owns channels 2L, 2L+1
  int c2 = lane * 2;
  __shared__ int s_idx[32];
  __shared__ float4 s_rel[32];
  const ushort_t* qkvb = qkv + (size_t)b * NPT * QKVW;
  if (lane < 32) {
    int j = knn[(size_t)u * 32 + lane];
    s_idx[lane] = j;
    const float* pn = pos + ((size_t)b * NPT + n) * 3;
    const float* pj = pos + ((size_t)b * NPT + j) * 3;
    s_rel[lane] = make_float4(pn[0] - pj[0], pn[1] - pj[1],
                              pn[2] - pj[2], 0.f);
  }
  __builtin_amdgcn_wave_barrier();
  asm volatile("s_waitcnt lgkmcnt(0)" ::: "memory");
  const float* Wp = g ? Wp1 : Wp0;
  const float* bp = g ? bp1 : bp0;
  float2 w0 = *(const float2*)(Wp + c2);
  float2 w1 = *(const float2*)(Wp + 128 + c2);
  float2 w2 = *(const float2*)(Wp + 256 + c2);
  float2 bb = *(const float2*)(bp + c2);
  unsigned pq = ((const unsigned*)(qkvb + (size_t)n * QKVW + g * 128))[lane];
  float qSx = bflo(pq) * SCALE, qSy = bfhi(pq) * SCALE;
  const ushort_t* kvbase = qkvb + 256 + g * 128;
  float num0 = 0.f, num1 = 0.f, den = 0.f;
  if (g == 0)
    attn_core<16>(kvbase, lane, s_idx, s_rel, qSx, qSy, w0, w1, w2, bb,
                  num0, num1, den);
  else
    attn_core<32>(kvbase, lane, s_idx, s_rel, qSx, qSy, w0, w1, w2, bb,
                  num0, num1, den);
  float inv = __builtin_amdgcn_rcpf(den);
  unsigned pk = (unsigned)f2bf(num0 * inv) | ((unsigned)f2bf(num1 * inv) << 16);
  ((unsigned*)xcat)[((size_t)b * NPT + n) * 128 + g * 64 + lane] = pk;
}

// ---------------------------------------------------------------------------
// MSF av only: S = part/2048 -> Z = gelu(S@Wfc1+b) -> a = Z@Wfc2+b ->
// av = pairwise softmax. One block per batch.
// ---------------------------------------------------------------------------
__global__ __launch_bounds__(256) void msf_av_kernel(
    const float* __restrict__ part, const float* __restrict__ Wfc1,
    const float* __restrict__ bfc1, const float* __restrict__ Wfc2,
    const float* __restrict__ bfc2, float* __restrict__ av_out) {
  int b = blockIdx.x, t = threadIdx.x;
  __shared__ float S[256], Z[128], A[256];
  S[t] = part[b * 256 + t] * (1.0f / 2048.0f);
  __syncthreads();
  if (t < 128) {
    float z = bfc1[t];
    for (int i = 0; i < 256; i++) z += S[i] * Wfc1[i * 128 + t];
    Z[t] = gelu_f(z);
  }
  __syncthreads();
  float a = bfc2[t];
  for (int j = 0; j < 128; j++) a += Z[j] * Wfc2[j * 256 + t];
  A[t] = a;
  __syncthreads();
  float pA = A[t ^ 128];
  float m = fmaxf(a, pA);
  float e = expf(a - m);
  av_out[b * 256 + t] = e / (e + expf(pA - m));
}

// ---------------------------------------------------------------------------
extern "C" void kernel_launch(void* const* d_in, const int* in_sizes, int n_in,
                              void* d_out, int out_size, void* d_ws, size_t ws_size,
                              hipStream_t stream) {
  const float* x     = (const float*)d_in[0];
  const float* pos   = (const float*)d_in[1];
  const float* Wqkv  = (const float*)d_in[2];
  const float* Wp0   = (const float*)d_in[3];
  const float* bp0   = (const float*)d_in[4];
  const float* Wp1   = (const float*)d_in[5];
  const float* bp1   = (const float*)d_in[6];
  const float* Wproj = (const float*)d_in[7];
  const float* bproj = (const float*)d_in[8];
  const float* Wfc1  = (const float*)d_in[9];
  const float* bfc1  = (const float*)d_in[10];
  const float* Wfc2  = (const float*)d_in[11];
  const float* bfc2  = (const float*)d_in[12];
  const float* Whead = (const float*)d_in[13];
  const float* bhead = (const float*)d_in[14];
  float* out = (float*)d_out;

  char* ws = (char*)d_ws;
  size_t off = 0;
  int* idx = (int*)(ws + off);              off += (size_t)B_ * NPT * 32 * 4;   // 1.0 MB
  ushort_t* qkv = (ushort_t*)(ws + off);    // bf16 qkv: 12.6 MB used
  float* fp = (float*)(ws + off);           // feats_proj (f32, 8.4 MB) reuses
  off += (size_t)B_ * NPT * QKVW * 4;       // region reserved at old 25.2 MB
  ushort_t* xbf = (ushort_t*)(ws + off);    off += (size_t)B_ * NPT * DIM_ * 2; // 4.2 MB
  ushort_t* xcat = xbf;  // xbf dead after gemm0
  ushort_t* WqkvT = (ushort_t*)(ws + off);  off += (size_t)QLEN * 2;
  ushort_t* WprojT = (ushort_t*)(ws + off); off += (size_t)PLEN * 2;
  ushort_t* WheadT = (ushort_t*)(ws + off); off += (size_t)PLEN * 2;
  float* part = (float*)(ws + off);         off += 1024 * 4;
  float* av = (float*)(ws + off);           off += 1024 * 4;

  const int M = B_ * NPT;  // 8192

  convert_kernel<<<2048, 256, 0, stream>>>(x, Wqkv, Wproj, Whead,
                                           xbf, WqkvT, WprojT, WheadT, part);
  knn_gemm0_kernel<<<2048, 256, 0, stream>>>(pos, idx, xbf, WqkvT, qkv);
  attn_kernel<<<dim3(M, 2), 64, 0, stream>>>(qkv, pos, idx,
                                             Wp0, bp0, Wp1, bp1, xcat);
  gemm_rf<1><<<1024, 64, 0, stream>>>(xcat, WprojT, bproj, nullptr,
                                      fp, part, nullptr, DIM_);
  msf_av_kernel<<<B_, 256, 0, stream>>>(part, Wfc1, bfc1, Wfc2, bfc2, av);
  gemm_rf<2><<<1024, 64, 0, stream>>>(xcat, WheadT, bhead, fp,
                                      out, nullptr, av, DIM_);
}

// Round 11
// 182.959 us; speedup vs baseline: 1.1458x; 1.1458x over previous
//
#include <hip/hip_runtime.h>
#include <cstdint>
#include <cstddef>

// Problem constants (reference: B=4, N=2048, DIM=256, heads=8, groups=2)
#define B_    4
#define NPT   2048
#define DIM_  256
#define QKVW  768   // 3*DIM
#define XLEN  2097152   // 8192*256
#define QLEN  196608    // 768*256
#define PLEN  65536     // 256*256
#define TOTC  (XLEN + QLEN + 2 * PLEN)  // 2424832

typedef unsigned short ushort_t;
typedef unsigned long long u64;
typedef short bf16x8 __attribute__((ext_vector_type(8)));
typedef float f32x4 __attribute__((ext_vector_type(4)));

__device__ __forceinline__ float gelu_f(float x) {
  return 0.5f * x * (1.0f + erff(x * 0.70710678118654752440f));
}

// Fast gelu: A&S 7.1.26 erf (max abs err 1.5e-7).
__device__ __forceinline__ float gelu_fast(float x) {
  const float is2 = 0.70710678118654752440f;
  float z = x * is2;
  float az = __builtin_fabsf(z);
  float t = __builtin_amdgcn_rcpf(fmaf(0.3275911f, az, 1.0f));
  float p = fmaf(1.061405429f, t, -1.453152027f);
  p = fmaf(p, t, 1.421413741f);
  p = fmaf(p, t, -0.284496736f);
  p = fmaf(p, t, 0.254829592f);
  p = p * t;
  float e = __expf(-az * az);
  float er = fmaf(-p, e, 1.0f);
  er = __builtin_copysignf(er, x);
  return 0.5f * x * (1.0f + er);
}

__device__ __forceinline__ ushort_t f2bf(float f) {
  unsigned u = __float_as_uint(f);
  unsigned r = (u + 0x7fffu + ((u >> 16) & 1u)) >> 16;
  return (ushort_t)r;
}
__device__ __forceinline__ float bf2f(ushort_t h) {
  return __uint_as_float(((unsigned)h) << 16);
}
// unpack a packed pair of bf16 (little-endian: low half = even channel)
__device__ __forceinline__ float bflo(unsigned p) {
  return __uint_as_float(p << 16);
}
__device__ __forceinline__ float bfhi(unsigned p) {
  return __uint_as_float(p & 0xffff0000u);
}

// butterfly sum over 16-lane rows via ds_swizzle (xor 1,2,4,8; and=0x1F).
// All 16 lanes of each row end with the row sum. LDS-pipe, no DPP hazards.
__device__ __forceinline__ float bfly16_sum(float x) {
  x += __int_as_float(__builtin_amdgcn_ds_swizzle(__float_as_int(x), 0x041F));
  x += __int_as_float(__builtin_amdgcn_ds_swizzle(__float_as_int(x), 0x081F));
  x += __int_as_float(__builtin_amdgcn_ds_swizzle(__float_as_int(x), 0x101F));
  x += __int_as_float(__builtin_amdgcn_ds_swizzle(__float_as_int(x), 0x201F));
  return x;
}

// scale a bf16x8 B-fragment by av[k] (8 consecutive k's from global, L1-hot)
__device__ __forceinline__ bf16x8 scale_bf(bf16x8 v, const float* avk) {
  bf16x8 r;
#pragma unroll
  for (int e = 0; e < 8; e++) {
    float f = bf2f((ushort_t)v[e]) * avk[e];
    r[e] = (short)f2bf(f);
  }
  return r;
}

// ---------------------------------------------------------------------------
// CONVERT: bf16 conversion of x and transposed weights; zeroes `part`.
// ---------------------------------------------------------------------------
__global__ __launch_bounds__(256) void convert_kernel(
    const float* __restrict__ x, const float* __restrict__ Wqkv,
    const float* __restrict__ Wproj, const float* __restrict__ Whead,
    ushort_t* __restrict__ xbf, ushort_t* __restrict__ WqkvT,
    ushort_t* __restrict__ WprojT, ushort_t* __restrict__ WheadT,
    float* __restrict__ part) {
  int base = blockIdx.x * 256 + threadIdx.x;
  if (base < 1024) part[base] = 0.f;
  for (int i = base; i < TOTC; i += 2048 * 256) {
    if (i < XLEN) {
      xbf[i] = f2bf(x[i]);
    } else if (i < XLEN + QLEN) {
      int e = i - XLEN;                  // input-major: coalesced read
      int k = e / 768, n = e - k * 768;
      WqkvT[n * 256 + k] = f2bf(Wqkv[e]);
    } else if (i < XLEN + QLEN + PLEN) {
      int e = i - XLEN - QLEN;
      int k = e >> 8, n = e & 255;
      WprojT[n * 256 + k] = f2bf(Wproj[e]);
    } else {
      int e = i - XLEN - QLEN - PLEN;
      int k = e >> 8, n = e & 255;
      WheadT[n * 256 + k] = f2bf(Whead[e]);
    }
  }
}

// ---------------------------------------------------------------------------
// FUSED KNN + GEMM0 v4 (R9 config, restored after R10 regression): grid
// 3072 x 256 thr. Waves 0-2 of block bid: ONE KNN query each (wq=bid*3+w,
// guard wq<8192). Wave 3: gemm0 tile bid. R10's 2-query-per-wave variant
// doubled dist state (64 VGPR) -> VGPR 108, occupancy 12.5%, knn 62us:
// in a latency-bound kernel occupancy IS the latency hiding -- ILP that
// costs waves is a net loss. Single-query + 3:1 wave mix measured 185 total.
// gemm0 stores C as bf16 (qkv 12.6 MB; halves attn gather fetch).
// KNN: ballot bisect seeded [0.0078, 0.25]; ballot+mbcnt compact;
// rank-select => exact argsort order (keys distinct via idx low bits).
// ---------------------------------------------------------------------------
__global__ __launch_bounds__(256) void knn_gemm0_kernel(
    const float* __restrict__ pos, int* __restrict__ idx_out,
    const ushort_t* __restrict__ A, const ushort_t* __restrict__ BT,
    ushort_t* __restrict__ C) {
  __shared__ u64 buf[3][128];
  int tid = threadIdx.x;
  int w = tid >> 6, lane = tid & 63;
  if (w == 3) {
    // ---- gemm0: C[64x32] = A @ BT^T (bf16 out), K=256, N=768 ----
    constexpr int K = 256;
    constexpr int N = 768;
    int quad = lane >> 4, r16 = lane & 15;
    int t0 = blockIdx.x;                           // 0..3071
    int m0 = (t0 / 24) * 64, n0 = (t0 % 24) * 32;
    const ushort_t* Ap = A + (size_t)(m0 + r16) * K + quad * 8;
    const ushort_t* Bp = BT + (size_t)(n0 + r16) * K + quad * 8;
    f32x4 acc[4][2] = {};
    bf16x8 af[4], bfv[2], af2[4], bf2[2];
#pragma unroll
    for (int i = 0; i < 4; i++) af[i] = *(const bf16x8*)(Ap + (size_t)i * 16 * K);
#pragma unroll
    for (int j = 0; j < 2; j++) bfv[j] = *(const bf16x8*)(Bp + (size_t)j * 16 * K);
#pragma unroll
    for (int kc = 0; kc < 8; kc++) {
      if (kc < 7) {
        int ko = (kc + 1) * 32;
#pragma unroll
        for (int i = 0; i < 4; i++)
          af2[i] = *(const bf16x8*)(Ap + (size_t)i * 16 * K + ko);
#pragma unroll
        for (int j = 0; j < 2; j++)
          bf2[j] = *(const bf16x8*)(Bp + (size_t)j * 16 * K + ko);
      }
#pragma unroll
      for (int i = 0; i < 4; i++) {
        acc[i][0] = __builtin_amdgcn_mfma_f32_16x16x32_bf16(af[i], bfv[0], acc[i][0], 0, 0, 0);
        acc[i][1] = __builtin_amdgcn_mfma_f32_16x16x32_bf16(af[i], bfv[1], acc[i][1], 0, 0, 0);
      }
#pragma unroll
      for (int i = 0; i < 4; i++) af[i] = af2[i];
      bfv[0] = bf2[0]; bfv[1] = bf2[1];
    }
#pragma unroll
    for (int i = 0; i < 4; i++) {
#pragma unroll
      for (int j = 0; j < 2; j++) {
        int col = n0 + j * 16 + r16;
#pragma unroll
        for (int r = 0; r < 4; r++) {
          int row = m0 + i * 16 + quad * 4 + r;
          C[(size_t)row * N + col] = f2bf(acc[i][j][r]);
        }
      }
    }
    return;
  }
  // ---- KNN query: wave w (0..2) handles wq = bid*3+w ----
  int wq = blockIdx.x * 3 + w;
  if (wq >= 8192) return;
  int b = wq >> 11, n = wq & (NPT - 1);
  const float* pb = pos + (size_t)b * NPT * 3;
  float qx = pb[n * 3 + 0], qy = pb[n * 3 + 1], qz = pb[n * 3 + 2];
  float dist[32];
  {
#pragma clang fp contract(off)
#pragma unroll
    for (int s = 0; s < 32; s++) {
      int j = lane + (s << 6);
      float dx = qx - pb[j * 3 + 0];
      float dy = qy - pb[j * 3 + 1];
      float dz = qz - pb[j * 3 + 2];
      float d = dx * dx;
      d = d + dy * dy;
      d = d + dz * dz;
      dist[s] = d;
    }
  }
  // --- bisect threshold T on dist bits: count(T) in [32, 64] (typ.) ---
  unsigned lo = 0x3C000000u;  // dist^2 = 0.0078 (r=0.088): count<32 typ.
  unsigned hi = 0x3E800001u;  // dist^2 = 0.25+  (r=0.5):   count>=32 certain
  for (int it = 0; it < 31 && hi - lo > 1; ++it) {
    unsigned mid = (lo + hi) >> 1;
    float fm = __uint_as_float(mid);   // positive floats: bit order == value order
    int c = 0;
#pragma unroll
    for (int s = 0; s < 32; s++)
      c += (int)__popcll(__ballot(dist[s] < fm));
    if (c >= 32) { hi = mid; if (c <= 64) break; }
    else lo = mid;
  }
  float fT = __uint_as_float(hi);      // invariant: count(T) >= 32
  // --- compact matching keys into wave-private LDS (ballot+mbcnt prefix) ---
  buf[w][lane] = ~0ULL;
  buf[w][lane + 64] = ~0ULL;
  __builtin_amdgcn_wave_barrier();
  asm volatile("s_waitcnt lgkmcnt(0)" ::: "memory");
  unsigned base = 0;
#pragma unroll
  for (int s = 0; s < 32; s++) {
    bool m = dist[s] < fT;
    u64 bal = __ballot(m);
    unsigned pre = __builtin_amdgcn_mbcnt_hi(
        (unsigned)(bal >> 32), __builtin_amdgcn_mbcnt_lo((unsigned)bal, 0u));
    unsigned p = base + pre;
    if (m && p < 128u) {
      int j = lane + (s << 6);
      buf[w][p] = ((u64)__float_as_uint(dist[s]) << 32) | (unsigned)j;
    }
    base += (unsigned)__popcll(bal);   // scalar accumulate
  }
  __builtin_amdgcn_wave_barrier();
  asm volatile("s_waitcnt lgkmcnt(0)" ::: "memory");
  unsigned total = base;               // wave-uniform
  if (total > 128u) total = 128u;
  unsigned mt = (total + 7u) & ~7u;    // buf[total..mt) are ~0 fillers
  // --- rank-select: rank = #keys smaller; rank<32 -> idx_out[rank] ---
  u64 k0 = buf[w][lane];
  u64 k1 = buf[w][lane + 64];
  int r0 = 0, r1 = 0;
  for (unsigned i = 0; i < mt; i += 8) {
#pragma unroll
    for (int t = 0; t < 8; t++) {
      u64 ki = buf[w][i + t];          // wave-uniform addr: LDS broadcast
      r0 += (ki < k0) ? 1 : 0;
      r1 += (ki < k1) ? 1 : 0;
    }
  }
  if (r0 < 32) idx_out[(size_t)wq * 32 + r0] = (int)(unsigned)(k0 & 0xffffffffULL);
  if (r1 < 32) idx_out[(size_t)wq * 32 + r1] = (int)(unsigned)(k1 & 0xffffffffULL);
}

// ---------------------------------------------------------------------------
// Register-file MFMA GEMM: ONE wave per 64x32 tile, K=256. No LDS/barriers.
// MODE 1: C = gelu(acc+bias) + colsum atomics (feats_proj)
// MODE 2: C = extra + (A@(B*av)) + bias (av from global, L1-hot)
// ---------------------------------------------------------------------------
template <int MODE>
__global__ __launch_bounds__(64, 4) void gemm_rf(
    const ushort_t* __restrict__ A, const ushort_t* __restrict__ BT,
    const float* __restrict__ bias, const float* __restrict__ extra,
    float* __restrict__ C, float* __restrict__ part,
    const float* __restrict__ av, int N) {
  constexpr int K = 256;
  int lane = threadIdx.x;
  int quad = lane >> 4, r16 = lane & 15;
  int t0 = blockIdx.x;
  int m0 = (t0 >> 3) * 64, n0 = (t0 & 7) * 32;
  int batch = m0 >> 11;
  const ushort_t* Ap = A + (size_t)(m0 + r16) * K + quad * 8;
  const ushort_t* Bp = BT + (size_t)(n0 + r16) * K + quad * 8;
  f32x4 acc[4][2] = {};
  bf16x8 af[4], bf[2], af2[4], bf2[2];
#pragma unroll
  for (int i = 0; i < 4; i++) af[i] = *(const bf16x8*)(Ap + (size_t)i * 16 * K);
#pragma unroll
  for (int j = 0; j < 2; j++) bf[j] = *(const bf16x8*)(Bp + (size_t)j * 16 * K);
#pragma unroll
  for (int kc = 0; kc < 8; kc++) {
    if (kc < 7) {
      int ko = (kc + 1) * 32;
#pragma unroll
      for (int i = 0; i < 4; i++)
        af2[i] = *(const bf16x8*)(Ap + (size_t)i * 16 * K + ko);
#pragma unroll
      for (int j = 0; j < 2; j++)
        bf2[j] = *(const bf16x8*)(Bp + (size_t)j * 16 * K + ko);
    }
    bf16x8 b0 = bf[0], b1 = bf[1];
    if (MODE == 2) {
      const float* avk = av + batch * 256 + kc * 32 + quad * 8;
      b0 = scale_bf(b0, avk);
      b1 = scale_bf(b1, avk);
    }
#pragma unroll
    for (int i = 0; i < 4; i++) {
      acc[i][0] = __builtin_amdgcn_mfma_f32_16x16x32_bf16(af[i], b0, acc[i][0], 0, 0, 0);
      acc[i][1] = __builtin_amdgcn_mfma_f32_16x16x32_bf16(af[i], b1, acc[i][1], 0, 0, 0);
    }
#pragma unroll
    for (int i = 0; i < 4; i++) af[i] = af2[i];
    bf[0] = bf2[0]; bf[1] = bf2[1];
  }
  float cs[2] = {};
#pragma unroll
  for (int i = 0; i < 4; i++) {
#pragma unroll
    for (int j = 0; j < 2; j++) {
      int col = n0 + j * 16 + r16;
#pragma unroll
      for (int r = 0; r < 4; r++) {
        int row = m0 + i * 16 + quad * 4 + r;
        float v = acc[i][j][r];
        if (MODE == 1) { v = gelu_fast(v + bias[col]); cs[j] += v; }
        else if (MODE == 2) v = extra[(size_t)row * 256 + col] + v + bias[col];
        C[(size_t)row * N + col] = v;
      }
    }
  }
  if (MODE == 1) {
#pragma unroll
    for (int j = 0; j < 2; j++) {
      cs[j] += __shfl_xor(cs[j], 16, 64);
      cs[j] += __shfl_xor(cs[j], 32, 64);
    }
    if (quad == 0) {
#pragma unroll
      for (int j = 0; j < 2; j++)
        atomicAdd(&part[batch * 256 + n0 + j * 16 + r16], cs[j]);
    }
  }
}

// ---------------------------------------------------------------------------
// Attention v9: XCD-batch-locality swizzle (kept from R10 -- mechanism:
// XCD x serves only batch x>>1, gather set k+v = 2 MB bf16 < 4 MB XCD-L2;
// measured neutral-to-positive in R10's confounded A/B). bf16 qkv;
// 2 ch/lane; 1-dword k/v pair loads; ds_swizzle butterfly; fixed-max SM.
// ---------------------------------------------------------------------------
template <int NK>
__device__ __forceinline__ void attn_core(
    const ushort_t* __restrict__ kvbase, int lane, const int* sidx,
    const float4* srel, float qSx, float qSy,
    float2 w0, float2 w1, float2 w2, float2 bb,
    float& num0, float& num1, float& den) {
#pragma unroll
  for (int j = 0; j < NK; j++) {
    int jj = __builtin_amdgcn_readfirstlane(sidx[j]);   // wave-uniform -> SGPR
    float4 rr = srel[j];                                // LDS broadcast
    const ushort_t* kb = kvbase + (size_t)jj * QKVW;
    unsigned pk = ((const unsigned*)kb)[lane];          // k pair (1 dword)
    unsigned pv = ((const unsigned*)(kb + 256))[lane];  // v pair (1 dword)
    float kvx = bflo(pk), kvy = bfhi(pk);
    float vvx = bflo(pv), vvy = bfhi(pv);
    float x0 = fmaf(rr.x, w0.x, fmaf(rr.y, w1.x, fmaf(rr.z, w2.x, bb.x)));
    float x1 = fmaf(rr.x, w0.y, fmaf(rr.y, w1.y, fmaf(rr.z, w2.y, bb.y)));
    // gelu_tanh(x) == x * sigmoid(x*(0.0713548163*x^2 + 1.5957691216))
    float z0 = x0 * fmaf(0.0713548163f, x0 * x0, 1.5957691216f);
    float z1 = x1 * fmaf(0.0713548163f, x1 * x1, 1.5957691216f);
    float r0 = x0 * __builtin_amdgcn_rcpf(1.0f + __expf(-z0));
    float r1 = x1 * __builtin_amdgcn_rcpf(1.0f + __expf(-z1));
    float p = fmaf(qSx, kvx, r0) + fmaf(qSy, kvy, r1);
    float logit = bfly16_sum(p);     // head sum over 32 ch, in all 16 lanes
    float e = __expf(logit);
    den += e;
    num0 = fmaf(e, vvx + r0, num0);
    num1 = fmaf(e, vvy + r1, num1);
  }
}

__global__ __launch_bounds__(64) void attn_kernel(
    const ushort_t* __restrict__ qkv, const float* __restrict__ pos,
    const int* __restrict__ knn,
    const float* __restrict__ Wp0, const float* __restrict__ bp0,
    const float* __restrict__ Wp1, const float* __restrict__ bp1,
    ushort_t* __restrict__ xcat) {
  const float SCALE = 0.17677669529663687f;  // 32^-0.5
  int bid = blockIdx.x;
  int xcd = bid & 7;            // XCD-batch-locality swizzle
  int b = xcd >> 1;             // XCD pair {2b,2b+1} serves batch b
  int n = ((bid >> 3) << 1) | (xcd & 1);
  int u = (b << 11) | n;        // original (b,n) index for knn/xcat
  int g = blockIdx.y;           // group
  int lane = threadIdx.x;       // 0..63, owns channels 2L, 2L+1
  int c2 = lane * 2;
  __shared__ int s_idx[32];
  __shared__ float4 s_rel[32];
  const ushort_t* qkvb = qkv + (size_t)b * NPT * QKVW;
  if (lane < 32) {
    int j = knn[(size_t)u * 32 + lane];
    s_idx[lane] = j;
    const float* pn = pos + ((size_t)b * NPT + n) * 3;
    const float* pj = pos + ((size_t)b * NPT + j) * 3;
    s_rel[lane] = make_float4(pn[0] - pj[0], pn[1] - pj[1],
                              pn[2] - pj[2], 0.f);
  }
  __builtin_amdgcn_wave_barrier();
  asm volatile("s_waitcnt lgkmcnt(0)" ::: "memory");
  const float* Wp = g ? Wp1 : Wp0;
  const float* bp = g ? bp1 : bp0;
  float2 w0 = *(const float2*)(Wp + c2);
  float2 w1 = *(const float2*)(Wp + 128 + c2);
  float2 w2 = *(const float2*)(Wp + 256 + c2);
  float2 bb = *(const float2*)(bp + c2);
  unsigned pq = ((const unsigned*)(qkvb + (size_t)n * QKVW + g * 128))[lane];
  float qSx = bflo(pq) * SCALE, qSy = bfhi(pq) * SCALE;
  const ushort_t* kvbase = qkvb + 256 + g * 128;
  float num0 = 0.f, num1 = 0.f, den = 0.f;
  if (g == 0)
    attn_core<16>(kvbase, lane, s_idx, s_rel, qSx, qSy, w0, w1, w2, bb,
                  num0, num1, den);
  else
    attn_core<32>(kvbase, lane, s_idx, s_rel, qSx, qSy, w0, w1, w2, bb,
                  num0, num1, den);
  float inv = __builtin_amdgcn_rcpf(den);
  unsigned pk = (unsigned)f2bf(num0 * inv) | ((unsigned)f2bf(num1 * inv) << 16);
  ((unsigned*)xcat)[((size_t)b * NPT + n) * 128 + g * 64 + lane] = pk;
}

// ---------------------------------------------------------------------------
// MSF av only: S = part/2048 -> Z = gelu(S@Wfc1+b) -> a = Z@Wfc2+b ->
// av = pairwise softmax. One block per batch.
// ---------------------------------------------------------------------------
__global__ __launch_bounds__(256) void msf_av_kernel(
    const float* __restrict__ part, const float* __restrict__ Wfc1,
    const float* __restrict__ bfc1, const float* __restrict__ Wfc2,
    const float* __restrict__ bfc2, float* __restrict__ av_out) {
  int b = blockIdx.x, t = threadIdx.x;
  __shared__ float S[256], Z[128], A[256];
  S[t] = part[b * 256 + t] * (1.0f / 2048.0f);
  __syncthreads();
  if (t < 128) {
    float z = bfc1[t];
    for (int i = 0; i < 256; i++) z += S[i] * Wfc1[i * 128 + t];
    Z[t] = gelu_f(z);
  }
  __syncthreads();
  float a = bfc2[t];
  for (int j = 0; j < 128; j++) a += Z[j] * Wfc2[j * 256 + t];
  A[t] = a;
  __syncthreads();
  float pA = A[t ^ 128];
  float m = fmaxf(a, pA);
  float e = expf(a - m);
  av_out[b * 256 + t] = e / (e + expf(pA - m));
}

// ---------------------------------------------------------------------------
extern "C" void kernel_launch(void* const* d_in, const int* in_sizes, int n_in,
                              void* d_out, int out_size, void* d_ws, size_t ws_size,
                              hipStream_t stream) {
  const float* x     = (const float*)d_in[0];
  const float* pos   = (const float*)d_in[1];
  const float* Wqkv  = (const float*)d_in[2];
  const float* Wp0   = (const float*)d_in[3];
  const float* bp0   = (const float*)d_in[4];
  const float* Wp1   = (const float*)d_in[5];
  const float* bp1   = (const float*)d_in[6];
  const float* Wproj = (const float*)d_in[7];
  const float* bproj = (const float*)d_in[8];
  const float* Wfc1  = (const float*)d_in[9];
  const float* bfc1  = (const float*)d_in[10];
  const float* Wfc2  = (const float*)d_in[11];
  const float* bfc2  = (const float*)d_in[12];
  const float* Whead = (const float*)d_in[13];
  const float* bhead = (const float*)d_in[14];
  float* out = (float*)d_out;

  char* ws = (char*)d_ws;
  size_t off = 0;
  int* idx = (int*)(ws + off);              off += (size_t)B_ * NPT * 32 * 4;   // 1.0 MB
  ushort_t* qkv = (ushort_t*)(ws + off);    // bf16 qkv: 12.6 MB used
  float* fp = (float*)(ws + off);           // feats_proj (f32, 8.4 MB) reuses
  off += (size_t)B_ * NPT * QKVW * 4;       // region reserved at old 25.2 MB
  ushort_t* xbf = (ushort_t*)(ws + off);    off += (size_t)B_ * NPT * DIM_ * 2; // 4.2 MB
  ushort_t* xcat = xbf;  // xbf dead after gemm0
  ushort_t* WqkvT = (ushort_t*)(ws + off);  off += (size_t)QLEN * 2;
  ushort_t* WprojT = (ushort_t*)(ws + off); off += (size_t)PLEN * 2;
  ushort_t* WheadT = (ushort_t*)(ws + off); off += (size_t)PLEN * 2;
  float* part = (float*)(ws + off);         off += 1024 * 4;
  float* av = (float*)(ws + off);           off += 1024 * 4;

  const int M = B_ * NPT;  // 8192

  convert_kernel<<<2048, 256, 0, stream>>>(x, Wqkv, Wproj, Whead,
                                           xbf, WqkvT, WprojT, WheadT, part);
  knn_gemm0_kernel<<<3072, 256, 0, stream>>>(pos, idx, xbf, WqkvT, qkv);
  attn_kernel<<<dim3(M, 2), 64, 0, stream>>>(qkv, pos, idx,
                                             Wp0, bp0, Wp1, bp1, xcat);
  gemm_rf<1><<<1024, 64, 0, stream>>>(xcat, WprojT, bproj, nullptr,
                                      fp, part, nullptr, DIM_);
  msf_av_kernel<<<B_, 256, 0, stream>>>(part, Wfc1, bfc1, Wfc2, bfc2, av);
  gemm_rf<2><<<1024, 64, 0, stream>>>(xcat, WheadT, bhead, fp,
                                      out, nullptr, av, DIM_);
}